// Round 3
// baseline (344.153 us; speedup 1.0000x reference)
//
#include <hip/hip_runtime.h>

#define H 10
#define T_LEN 2048
#define BATCH 8192

typedef float v2f __attribute__((ext_vector_type(2)));

__device__ __forceinline__ v2f vdup(float s) { v2f r; r.x = s; r.y = s; return r; }
__device__ __forceinline__ v2f vfma2(v2f a, v2f b, v2f c) {
    return __builtin_elementwise_fma(a, b, c);
}

// DPP row_ror:(2K): within each 16-lane row, dst lane i reads src lane (i-2K)&15.
// K MUST be a literal constant (builtin requirement) -- macro call sites only.
#define ROR2K(x, K) __int_as_float(__builtin_amdgcn_update_dpp(                  \
    0, __float_as_int(x), 0x120 + 2 * (K), 0xF, 0xF, true))

// Packed fp32 FMA, no broadcasts needed:
//   pkfma    : acc.lo += a.lo*b.lo ; acc.hi += a.hi*b.hi
//   pkfma_sw : acc.lo += a.hi*b.lo ; acc.hi += a.lo*b.hi   (src0 halves swapped
//              via VOP3P op_sel -- zero extra instructions for the swap)
__device__ __forceinline__ void pkfma(v2f& acc, v2f a, v2f b) {
    asm("v_pk_fma_f32 %0, %1, %2, %0 op_sel:[0,0,0] op_sel_hi:[1,1,1]"
        : "+v"(acc) : "v"(a), "v"(b));
}
__device__ __forceinline__ void pkfma_sw(v2f& acc, v2f a, v2f b) {
    asm("v_pk_fma_f32 %0, %1, %2, %0 op_sel:[1,0,0] op_sel_hi:[0,1,1]"
        : "+v"(acc) : "v"(a), "v"(b));
}

// ---------------------------------------------------------------------------
// Kernel 1: Bmat = expm(triu(A,1) - triu(A,1)^T) in fp64, write fp32 to ws.
// ---------------------------------------------------------------------------
__global__ void expm_kernel(const float* __restrict__ A, float* __restrict__ Bout) {
    __shared__ double S[H][H];
    __shared__ double P[H][H];
    __shared__ double E[H][H];
    const int tid = threadIdx.x;
    const int i = tid / H, j = tid % H;
    if (tid < H * H) {
        double a = 0.0;
        if (i < j) a = (double)A[i * H + j];
        else if (i > j) a = -(double)A[j * H + i];
        a *= (1.0 / 256.0);          // scale by 2^-8
        S[i][j] = a;
        P[i][j] = a;                 // S^1 / 1!
        E[i][j] = (i == j ? 1.0 : 0.0) + a;
    }
    __syncthreads();
    for (int k = 2; k <= 16; ++k) {
        double acc = 0.0;
        if (tid < H * H) {
            for (int m = 0; m < H; ++m) acc += P[i][m] * S[m][j];
            acc *= (1.0 / (double)k);
        }
        __syncthreads();
        if (tid < H * H) { P[i][j] = acc; E[i][j] += acc; }
        __syncthreads();
    }
    for (int rr = 0; rr < 8; ++rr) {
        double acc = 0.0;
        if (tid < H * H) {
            for (int m = 0; m < H; ++m) acc += E[i][m] * E[m][j];
        }
        __syncthreads();
        if (tid < H * H) E[i][j] = acc;
        __syncthreads();
    }
    if (tid < H * H) Bout[i * H + j] = (float)E[i][j];
}

// ---------------------------------------------------------------------------
// Kernel 2: DPP-exchange recurrence, packed-FP32 matvec.
// 8 lanes per batch (even/odd interleave in each 16-lane row), lane q owns
// h[2q],h[2q+1], H padded 10->16 (pads provably stay 0). Per step:
//   14 v_mov_dpp (7 rotations x {hx,hy})
// + 16 v_pk_fma_f32 (op_sel swap trick: 4 scalar products per rotation in
//   2 packed instrs, zero broadcast movs)
// + 4 scalar xproj + merge + 7-op modrelu  ==> ~47 instr ~= 94 cy issue/step.
// ---------------------------------------------------------------------------
__global__ __launch_bounds__(64)
void rnn_kernel(const float* __restrict__ x,
                const float* __restrict__ Bm,
                const float* __restrict__ Win,
                const float* __restrict__ bmod,
                const float* __restrict__ lW,
                const float* __restrict__ lb,
                float* __restrict__ out) {
    const int lane = threadIdx.x;
    const int l16  = lane & 15;
    const int row  = lane >> 4;       // 0..3
    const int par  = l16 & 1;         // batch parity within the row
    const int q    = l16 >> 1;        // 0..7 comb position
    const int bb   = blockIdx.x * 8 + row * 2 + par;   // 8192 = 1024*8 exact
    const int o0   = 2 * q, o1 = o0 + 1;               // owned components

    // Rotation k delivers (h[j0], h[j1]) of source m=(q-k)&7, j0=2m, j1=2m+1.
    // Bn[k] = {B[j0][o0], B[j1][o1]}  (normal pk_fma: lo*lo, hi*hi)
    // Bs[k] = {B[j1][o0], B[j0][o1]}  (swapped  pk_fma: hi*lo, lo*hi)
    v2f Bn[8], Bs[8];
#pragma unroll
    for (int k = 0; k < 8; ++k) {
        const int m = (q - k) & 7;
        const int j0 = 2 * m, j1 = j0 + 1;
        v2f bn = vdup(0.f), bs = vdup(0.f);
        if (o0 < H) {
            if (j0 < H) bn.x = Bm[j0 * H + o0];
            if (j1 < H) bs.x = Bm[j1 * H + o0];
        }
        if (o1 < H) {
            if (j1 < H) bn.y = Bm[j1 * H + o1];
            if (j0 < H) bs.y = Bm[j0 * H + o1];
        }
        Bn[k] = bn; Bs[k] = bs;
    }
    float w00 = 0.f, w01 = 0.f, w10 = 0.f, w11 = 0.f, bm0 = 0.f, bm1 = 0.f;
    if (o0 < H) { w00 = Win[o0 * 2]; w01 = Win[o0 * 2 + 1]; bm0 = bmod[o0]; }
    if (o1 < H) { w10 = Win[o1 * 2]; w11 = Win[o1 * 2 + 1]; bm1 = bmod[o1]; }

    float hx = 0.f, hy = 0.f;

    const float4* __restrict__ xp4 = (const float4*)(x + (size_t)bb * (T_LEN * 2));
    float4 buf[8];
#pragma unroll
    for (int i = 0; i < 8; ++i) buf[i] = xp4[i];

    for (int t0 = 0; t0 < T_LEN; t0 += 16) {
        float4 c[8];
#pragma unroll
        for (int i = 0; i < 8; ++i) c[i] = buf[i];
        if (t0 + 16 < T_LEN) {
            const int base = (t0 + 16) >> 1;
#pragma unroll
            for (int i = 0; i < 8; ++i) buf[i] = xp4[base + i];
        }

#pragma unroll
        for (int u = 0; u < 16; ++u) {
            const int ii = u >> 1;
            const float x0 = (u & 1) ? c[ii].z : c[ii].x;
            const float x1 = (u & 1) ? c[ii].w : c[ii].y;

            // rotations: straight-line, literal DPP controls
            v2f rt0, rt1, rt2, rt3, rt4, rt5, rt6, rt7;
            rt0.x = hx;           rt0.y = hy;
            rt1.x = ROR2K(hx, 1); rt1.y = ROR2K(hy, 1);
            rt2.x = ROR2K(hx, 2); rt2.y = ROR2K(hy, 2);
            rt3.x = ROR2K(hx, 3); rt3.y = ROR2K(hy, 3);
            rt4.x = ROR2K(hx, 4); rt4.y = ROR2K(hy, 4);
            rt5.x = ROR2K(hx, 5); rt5.y = ROR2K(hy, 5);
            rt6.x = ROR2K(hx, 6); rt6.y = ROR2K(hy, 6);
            rt7.x = ROR2K(hx, 7); rt7.y = ROR2K(hy, 7);

            // two accumulator chains; xproj (h-independent) seeds chain P early
            v2f accP, accQ;
            accP.x = fmaf(x1, w01, x0 * w00);
            accP.y = fmaf(x1, w11, x0 * w10);
            pkfma   (accP, rt0, Bn[0]);
            pkfma_sw(accP, rt0, Bs[0]);
            pkfma   (accP, rt1, Bn[1]);
            pkfma_sw(accP, rt1, Bs[1]);
            pkfma   (accP, rt2, Bn[2]);
            pkfma_sw(accP, rt2, Bs[2]);
            pkfma   (accP, rt3, Bn[3]);
            pkfma_sw(accP, rt3, Bs[3]);
            accQ = rt4 * Bn[4];
            pkfma_sw(accQ, rt4, Bs[4]);
            pkfma   (accQ, rt5, Bn[5]);
            pkfma_sw(accQ, rt5, Bs[5]);
            pkfma   (accQ, rt6, Bn[6]);
            pkfma_sw(accQ, rt6, Bs[6]);
            pkfma   (accQ, rt7, Bn[7]);
            pkfma_sw(accQ, rt7, Bs[7]);
            const v2f s = accP + accQ;

            const float rx = fmaxf(fabsf(s.x) + bm0, 0.f);
            const float ry = fmaxf(fabsf(s.y) + bm1, 0.f);
            hx = __builtin_copysignf(rx, s.x);
            hy = __builtin_copysignf(ry, s.y);
        }
    }

    // epilogue: out[bb][o] = lb[o] + sum_j h_j * lW[o][j], rotation gather
    v2f L0[8], L1[8];
#pragma unroll
    for (int k = 0; k < 8; ++k) {
        const int m = (q - k) & 7;
        const int j0 = 2 * m, j1 = j0 + 1;
        v2f a0 = vdup(0.f), a1 = vdup(0.f);
        if (o0 < H) {
            if (j0 < H) a0.x = lW[o0 * H + j0];
            if (j1 < H) a1.x = lW[o0 * H + j1];
        }
        if (o1 < H) {
            if (j0 < H) a0.y = lW[o1 * H + j0];
            if (j1 < H) a1.y = lW[o1 * H + j1];
        }
        L0[k] = a0; L1[k] = a1;
    }
    v2f accO = vdup(0.f);
    if (o0 < H) accO.x = lb[o0];
    if (o1 < H) accO.y = lb[o1];
    accO = vfma2(vdup(hx), L0[0], accO);
    accO = vfma2(vdup(hy), L1[0], accO);
#define OUTK(K) { const float ex_ = ROR2K(hx, K); const float ey_ = ROR2K(hy, K); \
                  accO = vfma2(vdup(ex_), L0[K], accO);                           \
                  accO = vfma2(vdup(ey_), L1[K], accO); }
    OUTK(1) OUTK(2) OUTK(3) OUTK(4) OUTK(5) OUTK(6) OUTK(7)
#undef OUTK
    if (o0 < H) {
        float2 st; st.x = accO.x; st.y = accO.y;
        *reinterpret_cast<float2*>(out + (size_t)bb * H + o0) = st;
    }
}

extern "C" void kernel_launch(void* const* d_in, const int* in_sizes, int n_in,
                              void* d_out, int out_size, void* d_ws, size_t ws_size,
                              hipStream_t stream) {
    const float* inputs = (const float*)d_in[0];  // [8192, 2048, 2]
    const float* A      = (const float*)d_in[1];  // [10, 10]
    const float* W_in   = (const float*)d_in[2];  // [10, 2]
    const float* b_mod  = (const float*)d_in[3];  // [10]
    const float* lin_W  = (const float*)d_in[4];  // [10, 10]
    const float* lin_b  = (const float*)d_in[5];  // [10]
    float* out = (float*)d_out;                   // [8192, 10]
    float* Bmat = (float*)d_ws;                   // 100 floats scratch

    expm_kernel<<<1, 128, 0, stream>>>(A, Bmat);
    rnn_kernel<<<BATCH / 8, 64, 0, stream>>>(inputs, Bmat, W_in, b_mod,
                                             lin_W, lin_b, out);
}